// Round 2
// baseline (22082.169 us; speedup 1.0000x reference)
//
#include <hip/hip_runtime.h>
#include <hip/hip_bf16.h>
#include <hip/hip_cooperative_groups.h>

namespace cg = cooperative_groups;

#define B_DIM 256
#define T_DIM 512
#define IN_DIM 1024
#define HID_DIM 1024
#define BLK 16384

typedef __attribute__((ext_vector_type(8))) short bf16x8;
typedef __attribute__((ext_vector_type(4))) float f32x4;

__device__ __forceinline__ unsigned short f2bf(float v) {
  unsigned int u = __float_as_uint(v);
  unsigned int r = (u + 0x7fffu + ((u >> 16) & 1u)) >> 16;
  return (unsigned short)r;
}

typedef __attribute__((address_space(3))) unsigned int lds_uint;
typedef const __attribute__((address_space(1))) unsigned int g_uint;
__device__ __forceinline__ void gload_lds16(const void* g, void* l) {
  __builtin_amdgcn_global_load_lds((g_uint*)g, (lds_uint*)l, 16, 0, 0);
}

// ---------------------------------------------------------------------------
// Pack W (4 gates, f32 [2048][1024]) into bf16 blocks for linear
// global_load_lds staging. Packed col in a 64-col block: g*16 + h_in.
// Block (cb, kc): [col 64][k' 128] bf16, byte = (col*256 + k'*2) ^ ((col&7)<<4)
// ---------------------------------------------------------------------------
__global__ void prep_pack_w(const float* __restrict__ Wi, const float* __restrict__ Wf,
                            const float* __restrict__ Wo, const float* __restrict__ Wc,
                            unsigned char* __restrict__ Wp) {
  const int bid = blockIdx.x;          // cb*16 + kc
  const int cb = bid >> 4, kc = bid & 15;
  const int tid = threadIdx.x;
  const int col = tid & 63;
  const int g = col >> 4, h_in = col & 15;
  const int kq = tid >> 6;
  const float* W = (g == 0) ? Wi : (g == 1) ? Wf : (g == 2) ? Wo : Wc;
  const float* src = W + (size_t)(kc * 128 + kq * 32) * HID_DIM + cb * 16 + h_in;
  unsigned char* dst = Wp + (size_t)bid * BLK;
  const unsigned int xo = (unsigned int)((col & 7) << 4);
#pragma unroll
  for (int b4 = 0; b4 < 4; ++b4) {
    unsigned short u[8];
#pragma unroll
    for (int j = 0; j < 8; ++j)
      u[j] = f2bf(src[(size_t)(b4 * 8 + j) * HID_DIM]);
    uint4 pk;
    pk.x = (unsigned)u[0] | ((unsigned)u[1] << 16);
    pk.y = (unsigned)u[2] | ((unsigned)u[3] << 16);
    pk.z = (unsigned)u[4] | ((unsigned)u[5] << 16);
    pk.w = (unsigned)u[6] | ((unsigned)u[7] << 16);
    unsigned int byte = ((unsigned int)(col * 256 + kq * 64 + b4 * 16)) ^ xo;
    *(uint4*)(dst + byte) = pk;
  }
}

__global__ void prep_bias(const float* __restrict__ bi, const float* __restrict__ bf_,
                          const float* __restrict__ bo, const float* __restrict__ bc,
                          float* __restrict__ bp) {
  int p = blockIdx.x * 256 + threadIdx.x;  // 0..4095
  int cbb = p >> 6, col = p & 63, g = col >> 4, h_in = col & 15;
  const float* b = (g == 0) ? bi : (g == 1) ? bf_ : (g == 2) ? bo : bc;
  bp[p] = b[cbb * 16 + h_in];
}

// Pack x (f32 [B][T][IN]) into bf16 swizzled chunk images:
// block bid = (t*4+mb)*8+kc, same [row 64][k' 128] swizzled layout as Wp.
__global__ void prep_pack_x(const float* __restrict__ x, unsigned char* __restrict__ xp) {
  const int bid = blockIdx.x;
  const int kc = bid & 7, mb = (bid >> 3) & 3, t = bid >> 5;
  const int tid = threadIdx.x;
  const int row = tid >> 2, kseg = tid & 3;
  const float* src = x + ((size_t)(mb * 64 + row) * T_DIM + t) * IN_DIM + kc * 128 + kseg * 32;
  unsigned char* dst = xp + (size_t)bid * BLK;
  const unsigned int xo = (unsigned)((row & 7) << 4);
#pragma unroll
  for (int c4 = 0; c4 < 4; ++c4) {
    float4 f0 = *(const float4*)(src + c4 * 8);
    float4 f1 = *(const float4*)(src + c4 * 8 + 4);
    uint4 pk;
    pk.x = (unsigned)f2bf(f0.x) | ((unsigned)f2bf(f0.y) << 16);
    pk.y = (unsigned)f2bf(f0.z) | ((unsigned)f2bf(f0.w) << 16);
    pk.z = (unsigned)f2bf(f1.x) | ((unsigned)f2bf(f1.y) << 16);
    pk.w = (unsigned)f2bf(f1.z) | ((unsigned)f2bf(f1.w) << 16);
    *(uint4*)(dst + (((unsigned)(row * 256 + kseg * 64 + c4 * 16)) ^ xo)) = pk;
  }
}

// ---------------------------------------------------------------------------
// Persistent cooperative LSTM: 256 WGs (one/CU), 4 waves each, loops t=0..511
// with one grid.sync per step. K=2048 per step in 16 chunks of 128; 4-buffer
// LDS ring, 3 chunks in flight, counted vmcnt (8 gload_lds per chunk/wave).
// c lives in registers; h ping-pongs between two swizzled bf16 global images.
// ---------------------------------------------------------------------------
__global__ __launch_bounds__(256, 1) void lstm_persist(
    const unsigned char* __restrict__ xp, const unsigned char* __restrict__ Wq,
    const float* __restrict__ bp, unsigned char* __restrict__ h0,
    unsigned char* __restrict__ h1, float* __restrict__ out) {
  extern __shared__ unsigned char ring[];  // 4 x (A 16K | B 16K) = 128 KB
  const int wg = blockIdx.x, mb = wg >> 6, cb = wg & 63;
  const int tid = threadIdx.x, lane = tid & 63, w = tid >> 6;
  const int wr = w >> 1, wc = w & 1;
  const int fr = lane & 15;
  const unsigned int koff2 = (unsigned)(lane >> 4) * 16;

  // epilogue mapping + persistent state
  const int erow = tid & 63;
  const int hb4 = (tid >> 6) * 4;
  float bI[4], bF[4], bO[4], bG[4];
#pragma unroll
  for (int j = 0; j < 4; ++j) {
    bI[j] = bp[cb * 64 + hb4 + j];
    bF[j] = bp[cb * 64 + 16 + hb4 + j];
    bO[j] = bp[cb * 64 + 32 + hb4 + j];
    bG[j] = bp[cb * 64 + 48 + hb4 + j];
  }
  float cr[4] = {0.f, 0.f, 0.f, 0.f};

  const unsigned char* WB = Wq + (size_t)cb * 16 * BLK + w * 4096 + lane * 16;

  cg::grid_group grid = cg::this_grid();

  for (int t = 0; t < T_DIM; ++t) {
    const unsigned char* hin = (t & 1) ? h1 : h0;
    unsigned char* hout = (t & 1) ? h0 : h1;
    const unsigned char* xA = xp + ((size_t)(t * 4 + mb)) * (8 * BLK) + w * 4096 + lane * 16;
    const unsigned char* hA = hin + (size_t)mb * (8 * BLK) + w * 4096 + lane * 16;

    f32x4 acc[2][2] = {{{0.f, 0.f, 0.f, 0.f}, {0.f, 0.f, 0.f, 0.f}},
                       {{0.f, 0.f, 0.f, 0.f}, {0.f, 0.f, 0.f, 0.f}}};

    auto issue = [&](int kc, int buf) {
      const unsigned char* sA = (kc < 8) ? xA + (size_t)kc * BLK
                                         : hA + (size_t)(kc - 8) * BLK;
      const unsigned char* sB = WB + (size_t)kc * BLK;
      unsigned char* dA = ring + buf * 32768 + w * 4096;
      unsigned char* dB = dA + BLK;
#pragma unroll
      for (int i = 0; i < 4; ++i) gload_lds16(sA + i * 1024, dA + i * 1024);
#pragma unroll
      for (int i = 0; i < 4; ++i) gload_lds16(sB + i * 1024, dB + i * 1024);
    };
    auto consume = [&](int buf) {
      const unsigned char* Ab = ring + buf * 32768;
      const unsigned char* Bb = Ab + BLK;
#pragma unroll
      for (int ks = 0; ks < 4; ++ks) {
        const unsigned int kb2 = (unsigned)ks * 64 + koff2;
        bf16x8 a[2], b[2];
#pragma unroll
        for (int m = 0; m < 2; ++m) {
          unsigned int row = (unsigned)(wr * 32 + m * 16 + fr);
          a[m] = *(const bf16x8*)(Ab + ((row * 256 + kb2) ^ ((row & 7) << 4)));
        }
#pragma unroll
        for (int n = 0; n < 2; ++n) {
          unsigned int col = (unsigned)(wc * 32 + n * 16 + fr);
          b[n] = *(const bf16x8*)(Bb + ((col * 256 + kb2) ^ ((col & 7) << 4)));
        }
#pragma unroll
        for (int m = 0; m < 2; ++m)
#pragma unroll
          for (int n = 0; n < 2; ++n)
            acc[m][n] = __builtin_amdgcn_mfma_f32_16x16x32_bf16(a[m], b[n], acc[m][n], 0, 0, 0);
      }
    };

    issue(0, 0); issue(1, 1); issue(2, 2);
#pragma unroll 1
    for (int kc = 0; kc < 13; ++kc) {
      issue(kc + 3, (kc + 3) & 3);
      asm volatile("s_waitcnt vmcnt(24)" ::: "memory");
      __builtin_amdgcn_s_barrier();
      asm volatile("" ::: "memory");
      consume(kc & 3);
      __builtin_amdgcn_s_barrier();
      asm volatile("" ::: "memory");
    }
    asm volatile("s_waitcnt vmcnt(16)" ::: "memory");
    __builtin_amdgcn_s_barrier();
    asm volatile("" ::: "memory");
    consume(1);
    __builtin_amdgcn_s_barrier();
    asm volatile("" ::: "memory");
    asm volatile("s_waitcnt vmcnt(8)" ::: "memory");
    __builtin_amdgcn_s_barrier();
    asm volatile("" ::: "memory");
    consume(2);
    __builtin_amdgcn_s_barrier();
    asm volatile("" ::: "memory");
    asm volatile("s_waitcnt vmcnt(0)" ::: "memory");
    __builtin_amdgcn_s_barrier();
    asm volatile("" ::: "memory");
    consume(3);

    // ----- gate exchange (pad 65 to kill the stride-64 bank conflict) -----
    float* gates = (float*)ring;  // 64x65 f32 = 16.6 KB, overlays buf0 (free)
#pragma unroll
    for (int m = 0; m < 2; ++m)
#pragma unroll
      for (int n = 0; n < 2; ++n)
#pragma unroll
        for (int j = 0; j < 4; ++j) {
          int row = wr * 32 + m * 16 + (lane >> 4) * 4 + j;
          int col = wc * 32 + n * 16 + fr;
          gates[row * 65 + col] = acc[m][n][j];
        }
    __syncthreads();
    float hv[4];
#pragma unroll
    for (int j = 0; j < 4; ++j) {
      int hc = hb4 + j;
      float pi = gates[erow * 65 + hc] + bI[j];
      float pf = gates[erow * 65 + 16 + hc] + bF[j];
      float po = gates[erow * 65 + 32 + hc] + bO[j];
      float pg = gates[erow * 65 + 48 + hc] + bG[j];
      float ig = 1.f / (1.f + __expf(-pi));
      float fg = 1.f / (1.f + __expf(-pf));
      float og = 1.f / (1.f + __expf(-po));
      float gg = 1.f - 2.f / (1.f + __expf(2.f * pg));  // tanh
      float cn = fg * cr[j] + ig * gg;
      cr[j] = cn;
      float th = 1.f - 2.f / (1.f + __expf(2.f * cn));
      hv[j] = og * th;
    }
    {  // write h to next step's swizzled image (4 bf16 = 8 B, aligned)
      int hcg = cb * 16 + hb4;
      int kc2 = hcg >> 7, kp = hcg & 127;
      unsigned int byte = ((unsigned)(erow * 256 + kp * 2)) ^ ((unsigned)((erow & 7) << 4));
      uint2 pk;
      pk.x = (unsigned)f2bf(hv[0]) | ((unsigned)f2bf(hv[1]) << 16);
      pk.y = (unsigned)f2bf(hv[2]) | ((unsigned)f2bf(hv[3]) << 16);
      *(uint2*)(hout + (size_t)(mb * 8 + kc2) * BLK + byte) = pk;
    }
    if (t == T_DIM - 1) {
      size_t gidx = (size_t)(mb * 64 + erow) * HID_DIM + cb * 16 + hb4;
      *(float4*)(out + gidx) = make_float4(hv[0], hv[1], hv[2], hv[3]);
      *(float4*)(out + (size_t)B_DIM * HID_DIM + gidx) = make_float4(cr[0], cr[1], cr[2], cr[3]);
    }
    grid.sync();
  }
}

// ---------------------------------------------------------------------------
// Fallback (round-1) per-step kernel, used only if ws_size is too small for
// the packed-x persistent path.
// ---------------------------------------------------------------------------
__global__ __launch_bounds__(256) void lstm_step(
    const float* __restrict__ x, const unsigned char* __restrict__ Wp,
    const float* __restrict__ bp, const unsigned char* __restrict__ hin,
    unsigned char* __restrict__ hout, float* __restrict__ cst,
    float* __restrict__ out, int t) {
  __shared__ unsigned char smem[65536];
  const int wg = blockIdx.x, mb = wg >> 6, cb = wg & 63;
  const int tid = threadIdx.x, lane = tid & 63, w = tid >> 6;
  const int NC = (t == 0) ? 8 : 16;

  f32x4 acc[2][2] = {{{0.f,0.f,0.f,0.f},{0.f,0.f,0.f,0.f}},
                     {{0.f,0.f,0.f,0.f},{0.f,0.f,0.f,0.f}}};

  const int xrow = tid >> 2, kseg = tid & 3;
  const float* xbase = x + ((size_t)(mb * 64 + xrow) * T_DIM + t) * IN_DIM + kseg * 32;
  float4 fx[8];

  auto issueX = [&](int kc) {
    const float4* s = (const float4*)(xbase + kc * 128);
#pragma unroll
    for (int v = 0; v < 8; ++v) fx[v] = s[v];
  };
  auto writeX = [&](int q) {
    unsigned char* Ab = smem + q * 32768;
    const unsigned int base = (unsigned int)(xrow * 256 + kseg * 64);
    const unsigned int xo = (unsigned int)((xrow & 7) << 4);
#pragma unroll
    for (int c4 = 0; c4 < 4; ++c4) {
      const float* f = (const float*)&fx[c4 * 2];
      uint4 pk;
      pk.x = (unsigned)f2bf(f[0]) | ((unsigned)f2bf(f[1]) << 16);
      pk.y = (unsigned)f2bf(f[2]) | ((unsigned)f2bf(f[3]) << 16);
      pk.z = (unsigned)f2bf(f[4]) | ((unsigned)f2bf(f[5]) << 16);
      pk.w = (unsigned)f2bf(f[6]) | ((unsigned)f2bf(f[7]) << 16);
      *(uint4*)(Ab + ((base + c4 * 16) ^ xo)) = pk;
    }
  };
  auto issueH = [&](int kc, int q) {
    const unsigned char* s = hin + ((size_t)(mb * 8 + (kc - 8))) * BLK + w * 4096 + lane * 16;
    unsigned char* d = smem + q * 32768 + w * 4096;
#pragma unroll
    for (int i = 0; i < 4; ++i) gload_lds16(s + i * 1024, d + i * 1024);
  };
  auto issueB = [&](int kc, int q) {
    const unsigned char* s = Wp + ((size_t)(cb * 16 + kc)) * BLK + w * 4096 + lane * 16;
    unsigned char* d = smem + q * 32768 + BLK + w * 4096;
#pragma unroll
    for (int i = 0; i < 4; ++i) gload_lds16(s + i * 1024, d + i * 1024);
  };

  const int wr = w >> 1, wc = w & 1;
  const int fr = lane & 15, koff = (lane >> 4) * 8;
  auto consume = [&](int q) {
    const unsigned char* Ab = smem + q * 32768;
    const unsigned char* Bb = Ab + BLK;
#pragma unroll
    for (int ks = 0; ks < 4; ++ks) {
      const unsigned int kb2 = (unsigned)(ks * 32 + koff) * 2;
      bf16x8 a[2], b[2];
#pragma unroll
      for (int m = 0; m < 2; ++m) {
        unsigned int row = (unsigned)(wr * 32 + m * 16 + fr);
        a[m] = *(const bf16x8*)(Ab + ((row * 256 + kb2) ^ ((row & 7) << 4)));
      }
#pragma unroll
      for (int n = 0; n < 2; ++n) {
        unsigned int col = (unsigned)(wc * 32 + n * 16 + fr);
        b[n] = *(const bf16x8*)(Bb + ((col * 256 + kb2) ^ ((col & 7) << 4)));
      }
#pragma unroll
      for (int m = 0; m < 2; ++m)
#pragma unroll
        for (int n = 0; n < 2; ++n)
          acc[m][n] = __builtin_amdgcn_mfma_f32_16x16x32_bf16(a[m], b[n], acc[m][n], 0, 0, 0);
    }
  };

  issueX(0); issueB(0, 0); writeX(0);
  __syncthreads();
  for (int kc = 0; kc < NC; ++kc) {
    const int q = kc & 1, qn = q ^ 1;
    const bool more = (kc + 1 < NC);
    const bool nx = more && (kc + 1 < 8);
    if (more) {
      issueB(kc + 1, qn);
      if (nx) issueX(kc + 1); else issueH(kc + 1, qn);
    }
    consume(q);
    if (nx) writeX(qn);
    __syncthreads();
  }

  float* gates = (float*)smem;
#pragma unroll
  for (int m = 0; m < 2; ++m)
#pragma unroll
    for (int n = 0; n < 2; ++n)
#pragma unroll
      for (int j = 0; j < 4; ++j) {
        int row = wr * 32 + m * 16 + (lane >> 4) * 4 + j;
        int col = wc * 32 + n * 16 + fr;
        gates[row * 65 + col] = acc[m][n][j];
      }
  __syncthreads();
  {
    const int row = tid & 63, hsel = tid >> 6;
    const int hb = hsel * 4;
    const size_t gidx = (size_t)(mb * 64 + row) * HID_DIM + cb * 16 + hb;
    float cold[4] = {0.f, 0.f, 0.f, 0.f};
    if (t > 0) *(float4*)cold = *(const float4*)(cst + gidx);
    float hv[4], cv[4];
#pragma unroll
    for (int j = 0; j < 4; ++j) {
      int hc = hb + j;
      float pi = gates[row * 65 + hc]      + bp[cb * 64 + hc];
      float pf = gates[row * 65 + 16 + hc] + bp[cb * 64 + 16 + hc];
      float po = gates[row * 65 + 32 + hc] + bp[cb * 64 + 32 + hc];
      float pg = gates[row * 65 + 48 + hc] + bp[cb * 64 + 48 + hc];
      float ig = 1.f / (1.f + __expf(-pi));
      float fg = 1.f / (1.f + __expf(-pf));
      float og = 1.f / (1.f + __expf(-po));
      float gg = tanhf(pg);
      float cn = fg * cold[j] + ig * gg;
      cv[j] = cn;
      hv[j] = og * tanhf(cn);
    }
    *(float4*)(cst + gidx) = *(const float4*)cv;
    {
      int hcg = cb * 16 + hb;
      int kc2 = hcg >> 7, kp = hcg & 127;
      unsigned int byte = ((unsigned)(row * 256 + kp * 2)) ^ ((unsigned)((row & 7) << 4));
      uint2 pk;
      pk.x = (unsigned)f2bf(hv[0]) | ((unsigned)f2bf(hv[1]) << 16);
      pk.y = (unsigned)f2bf(hv[2]) | ((unsigned)f2bf(hv[3]) << 16);
      *(uint2*)(hout + ((size_t)(mb * 8 + kc2)) * BLK + byte) = pk;
    }
    if (t == T_DIM - 1) {
      *(float4*)(out + gidx) = *(const float4*)hv;
      *(float4*)(out + (size_t)B_DIM * HID_DIM + gidx) = *(const float4*)cv;
    }
  }
}

extern "C" void kernel_launch(void* const* d_in, const int* in_sizes, int n_in,
                              void* d_out, int out_size, void* d_ws, size_t ws_size,
                              hipStream_t stream) {
  (void)in_sizes; (void)n_in; (void)out_size;
  const float* x   = (const float*)d_in[0];
  const float* Wf_ = (const float*)d_in[1];
  const float* bf_ = (const float*)d_in[2];
  const float* Wi_ = (const float*)d_in[3];
  const float* bi_ = (const float*)d_in[4];
  const float* Wo_ = (const float*)d_in[5];
  const float* bo_ = (const float*)d_in[6];
  const float* Wc_ = (const float*)d_in[7];
  const float* bc_ = (const float*)d_in[8];

  unsigned char* ws = (unsigned char*)d_ws;
  unsigned char* Wp = ws;                                   // 16 MB packed bf16 W
  float* bp = (float*)(ws + 16777216);                      // 16 KB packed f32 bias
  unsigned char* h0 = ws + 16777216 + 16384;                // 512 KB h image A
  unsigned char* h1 = h0 + 524288;                          // 512 KB h image B
  float* cst = (float*)(h1 + 524288);                       // 1 MB (fallback only)
  unsigned char* xp = (unsigned char*)(ws + 16777216 + 16384 + 524288 + 524288 + 1048576);
  const size_t NEED = 16777216ull + 16384 + 524288 + 524288 + 1048576 + 268435456ull;
  float* out = (float*)d_out;

  prep_pack_w<<<1024, 256, 0, stream>>>(Wi_, Wf_, Wo_, Wc_, Wp);
  prep_bias<<<16, 256, 0, stream>>>(bi_, bf_, bo_, bc_, bp);

  if (ws_size >= NEED) {
    prep_pack_x<<<16384, 256, 0, stream>>>(x, xp);
    hipMemsetAsync(h0, 0, 524288, stream);
    hipFuncSetAttribute((const void*)lstm_persist,
                        hipFuncAttributeMaxDynamicSharedMemorySize, 131072);
    const unsigned char* a_xp = xp;
    const unsigned char* a_wp = Wp;
    const float* a_bp = bp;
    unsigned char* a_h0 = h0;
    unsigned char* a_h1 = h1;
    float* a_out = out;
    void* args[] = {&a_xp, &a_wp, &a_bp, &a_h0, &a_h1, &a_out};
    hipLaunchCooperativeKernel((const void*)lstm_persist, dim3(256), dim3(256),
                               args, 131072u, stream);
  } else {
    for (int t = 0; t < T_DIM; ++t) {
      unsigned char* hin  = (t & 1) ? h1 : h0;
      unsigned char* hout = (t & 1) ? h0 : h1;
      lstm_step<<<256, 256, 0, stream>>>(x, Wp, bp, hin, hout, cst, out, t);
    }
  }
}

// Round 3
// 11141.077 us; speedup vs baseline: 1.9820x; 1.9820x over previous
//
#include <hip/hip_runtime.h>
#include <hip/hip_bf16.h>
#include <hip/hip_cooperative_groups.h>

#define B_DIM 256
#define T_DIM 512
#define IN_DIM 1024
#define HID_DIM 1024
#define BLK 16384

typedef __attribute__((ext_vector_type(8))) short bf16x8;
typedef __attribute__((ext_vector_type(4))) float f32x4;

__device__ __forceinline__ unsigned short f2bf(float v) {
  unsigned int u = __float_as_uint(v);
  unsigned int r = (u + 0x7fffu + ((u >> 16) & 1u)) >> 16;
  return (unsigned short)r;
}

typedef __attribute__((address_space(3))) unsigned int lds_uint;
typedef const __attribute__((address_space(1))) unsigned int g_uint;
__device__ __forceinline__ void gload_lds16(const void* g, void* l) {
  __builtin_amdgcn_global_load_lds((g_uint*)g, (lds_uint*)l, 16, 0, 0);
}

// src includes the per-lane offset (lane*16); dst is the wave-uniform base
// (HW adds lane*16 itself for global_load_lds).
__device__ __forceinline__ void glds4(const unsigned char* s, unsigned char* d) {
#pragma unroll
  for (int i = 0; i < 4; ++i) gload_lds16(s + i * 1024, d + i * 1024);
}

__device__ __forceinline__ void h_load(unsigned long long (&r)[8],
                                       const unsigned char* src) {
#pragma unroll
  for (int p = 0; p < 8; ++p)
    r[p] = __hip_atomic_load((const unsigned long long*)(src + p * 512),
                             __ATOMIC_RELAXED, __HIP_MEMORY_SCOPE_AGENT);
}

__device__ __forceinline__ void h_write(unsigned long long (&r)[8],
                                        unsigned char* dst) {
#pragma unroll
  for (int p = 0; p < 8; ++p)
    *(unsigned long long*)(dst + p * 512) = r[p];
  asm volatile("s_waitcnt lgkmcnt(0)" ::: "memory");
}

__device__ __forceinline__ void spin_ge(unsigned int* p, unsigned int tgt) {
  while (__hip_atomic_fetch_add(p, 0u, __ATOMIC_RELAXED,
                                __HIP_MEMORY_SCOPE_AGENT) < tgt)
    __builtin_amdgcn_s_sleep(8);
  asm volatile("" ::: "memory");
}

// ---------------------------------------------------------------------------
// Pack W (4 gates, f32 [2048][1024]) into bf16 blocks for linear
// global_load_lds staging. Packed col in a 64-col block: g*16 + h_in.
// Block (cb, kc): [col 64][k' 128] bf16, byte = (col*256 + k'*2) ^ ((col&7)<<4)
// ---------------------------------------------------------------------------
__global__ void prep_pack_w(const float* __restrict__ Wi, const float* __restrict__ Wf,
                            const float* __restrict__ Wo, const float* __restrict__ Wc,
                            unsigned char* __restrict__ Wp) {
  const int bid = blockIdx.x;          // cb*16 + kc
  const int cb = bid >> 4, kc = bid & 15;
  const int tid = threadIdx.x;
  const int col = tid & 63;
  const int g = col >> 4, h_in = col & 15;
  const int kq = tid >> 6;
  const float* W = (g == 0) ? Wi : (g == 1) ? Wf : (g == 2) ? Wo : Wc;
  const float* src = W + (size_t)(kc * 128 + kq * 32) * HID_DIM + cb * 16 + h_in;
  unsigned char* dst = Wp + (size_t)bid * BLK;
  const unsigned int xo = (unsigned int)((col & 7) << 4);
#pragma unroll
  for (int b4 = 0; b4 < 4; ++b4) {
    unsigned short u[8];
#pragma unroll
    for (int j = 0; j < 8; ++j)
      u[j] = f2bf(src[(size_t)(b4 * 8 + j) * HID_DIM]);
    uint4 pk;
    pk.x = (unsigned)u[0] | ((unsigned)u[1] << 16);
    pk.y = (unsigned)u[2] | ((unsigned)u[3] << 16);
    pk.z = (unsigned)u[4] | ((unsigned)u[5] << 16);
    pk.w = (unsigned)u[6] | ((unsigned)u[7] << 16);
    unsigned int byte = ((unsigned int)(col * 256 + kq * 64 + b4 * 16)) ^ xo;
    *(uint4*)(dst + byte) = pk;
  }
}

__global__ void prep_bias(const float* __restrict__ bi, const float* __restrict__ bf_,
                          const float* __restrict__ bo, const float* __restrict__ bc,
                          float* __restrict__ bp) {
  int p = blockIdx.x * 256 + threadIdx.x;  // 0..4095
  int cbb = p >> 6, col = p & 63, g = col >> 4, h_in = col & 15;
  const float* b = (g == 0) ? bi : (g == 1) ? bf_ : (g == 2) ? bo : bc;
  bp[p] = b[cbb * 16 + h_in];
}

// Pack x (f32 [B][T][IN]) into bf16 swizzled chunk images:
// block bid = (t*4+mb)*8+kc, same [row 64][k' 128] swizzled layout as Wp.
__global__ void prep_pack_x(const float* __restrict__ x, unsigned char* __restrict__ xp) {
  const int bid = blockIdx.x;
  const int kc = bid & 7, mb = (bid >> 3) & 3, t = bid >> 5;
  const int tid = threadIdx.x;
  const int row = tid >> 2, kseg = tid & 3;
  const float* src = x + ((size_t)(mb * 64 + row) * T_DIM + t) * IN_DIM + kc * 128 + kseg * 32;
  unsigned char* dst = xp + (size_t)bid * BLK;
  const unsigned int xo = (unsigned)((row & 7) << 4);
#pragma unroll
  for (int c4 = 0; c4 < 4; ++c4) {
    float4 f0 = *(const float4*)(src + c4 * 8);
    float4 f1 = *(const float4*)(src + c4 * 8 + 4);
    uint4 pk;
    pk.x = (unsigned)f2bf(f0.x) | ((unsigned)f2bf(f0.y) << 16);
    pk.y = (unsigned)f2bf(f0.z) | ((unsigned)f2bf(f0.w) << 16);
    pk.z = (unsigned)f2bf(f1.x) | ((unsigned)f2bf(f1.y) << 16);
    pk.w = (unsigned)f2bf(f1.z) | ((unsigned)f2bf(f1.w) << 16);
    *(uint4*)(dst + (((unsigned)(row * 256 + kseg * 64 + c4 * 16)) ^ xo)) = pk;
  }
}

// ---------------------------------------------------------------------------
// Persistent LSTM, NO grid.sync. 256 WGs (1/CU) x 512 threads (8 waves,
// 2 waves/SIMD). Per step: 16 K-chunks of 128; x & W staged via
// global_load_lds (counted vmcnt pipeline, 4-buffer LDS ring); h exchanged
// through a ring-3 of global bf16 images with agent-scope atomics + per-step
// producer/consumer counters (sync is only within each 64-WG mb-group).
// ---------------------------------------------------------------------------
__global__ __launch_bounds__(512, 1) void lstm_persist(
    const unsigned char* __restrict__ xp, const unsigned char* __restrict__ Wq,
    const float* __restrict__ bp, unsigned char* hring,
    unsigned int* prodCnt, unsigned int* consCnt, float* __restrict__ out) {
  extern __shared__ unsigned char ring[];  // 4 x (A 16K | B 16K) = 128 KB
  const int wg = blockIdx.x, mb = wg >> 6, cb = wg & 63;
  const int tid = threadIdx.x, lane = tid & 63, w = tid >> 6;
  const int wr = w >> 2, wc = w & 3;       // 2x4 wave grid over 64x64 tile
  const int fr = lane & 15;
  const unsigned koff2 = (unsigned)((lane >> 4) << 4);  // k-sub byte offset

  // epilogue mapping + persistent per-thread state (2 h-cols each)
  const int erow = tid & 63, hb2 = (tid >> 6) * 2;
  float bI[2], bF[2], bO[2], bG[2];
#pragma unroll
  for (int j = 0; j < 2; ++j) {
    bI[j] = bp[cb * 64 + hb2 + j];
    bF[j] = bp[cb * 64 + 16 + hb2 + j];
    bO[j] = bp[cb * 64 + 32 + hb2 + j];
    bG[j] = bp[cb * 64 + 48 + hb2 + j];
  }
  float cr[2] = {0.f, 0.f};

  const unsigned char* WB = Wq + (size_t)(cb * 16) * BLK;
  unsigned long long hA[8], hB[8];

#pragma unroll 1
  for (int t = 0; t < T_DIM; ++t) {
    const int NC = (t == 0) ? 8 : 16;
    const unsigned char* xA =
        xp + ((size_t)(t * 4 + mb)) * (8 * BLK) + w * 4096 + lane * 16;
    const unsigned char* hSrc =
        hring + (size_t)((t + 2) % 3) * 524288 +          // slot (t-1)%3
        (size_t)(mb * 8) * BLK + w * 4096 + lane * 8;     // + (kc-8)*BLK later

    f32x4 acc[2] = {{0.f, 0.f, 0.f, 0.f}, {0.f, 0.f, 0.f, 0.f}};

    auto consume = [&](int buf) {
      const unsigned char* Ab = ring + buf * 32768;
      const unsigned char* Bb = Ab + BLK;
#pragma unroll
      for (int ks = 0; ks < 4; ++ks) {
        const unsigned kb2 = (unsigned)ks * 64 + koff2;
        const unsigned r0 = (unsigned)(wr * 32 + fr), r1 = r0 + 16;
        const unsigned cl = (unsigned)(wc * 16 + fr);
        bf16x8 a0 = *(const bf16x8*)(Ab + ((r0 * 256 + kb2) ^ ((r0 & 7) << 4)));
        bf16x8 a1 = *(const bf16x8*)(Ab + ((r1 * 256 + kb2) ^ ((r1 & 7) << 4)));
        bf16x8 b0 = *(const bf16x8*)(Bb + ((cl * 256 + kb2) ^ ((cl & 7) << 4)));
        acc[0] = __builtin_amdgcn_mfma_f32_16x16x32_bf16(a0, b0, acc[0], 0, 0, 0);
        acc[1] = __builtin_amdgcn_mfma_f32_16x16x32_bf16(a1, b0, acc[1], 0, 0, 0);
      }
    };

    // prologue: issue x-chunks 0..2
    if (w < 4) {
#pragma unroll
      for (int c = 0; c < 3; ++c)
        glds4(xA + (size_t)c * BLK, ring + c * 32768 + (w << 12));
    } else {
#pragma unroll
      for (int c = 0; c < 3; ++c)
        glds4(WB + (size_t)c * BLK + ((w - 4) << 12) + lane * 16,
              ring + c * 32768 + BLK + ((w - 4) << 12));
    }

#pragma unroll 1
    for (int kc = 0; kc < NC; ++kc) {
      const int nx = kc + 3;
      const bool isq = nx < NC;
      if (isq && nx == 8) {  // before first h loads: wait for producers
        if (lane == 0) spin_ge(&prodCnt[(t - 1) * 4 + mb], 64u);
        __builtin_amdgcn_sched_barrier(0);
      }
      if (w < 4) {
        if (isq && nx < 8)
          glds4(xA + (size_t)nx * BLK, ring + (nx & 3) * 32768 + (w << 12));
        if (kc + 1 >= 8 && kc + 1 < NC) {  // ds_write h chunk kc+1
          unsigned char* d = ring + ((kc + 1) & 3) * 32768 + (w << 12) + lane * 8;
          if (((kc + 1) & 1) == 0) h_write(hA, d);
          else h_write(hB, d);
        }
        if (isq && nx >= 8) {              // atomic-load h chunk nx
          const unsigned char* s = hSrc + (size_t)(nx - 8) * BLK;
          if ((nx & 1) == 0) h_load(hA, s);
          else h_load(hB, s);
        }
      } else {
        if (isq)
          glds4(WB + (size_t)nx * BLK + ((w - 4) << 12) + lane * 16,
                ring + (nx & 3) * 32768 + BLK + ((w - 4) << 12));
      }
      const int ahead = NC - 1 - kc;
      if (ahead >= 3)      asm volatile("s_waitcnt vmcnt(12)" ::: "memory");
      else if (ahead == 2) asm volatile("s_waitcnt vmcnt(8)" ::: "memory");
      else if (ahead == 1) asm volatile("s_waitcnt vmcnt(4)" ::: "memory");
      else                 asm volatile("s_waitcnt vmcnt(0)" ::: "memory");
      __builtin_amdgcn_s_barrier();
      consume(kc & 3);
      __builtin_amdgcn_s_barrier();
    }

    // ----- gate exchange (pad 65: no stride-64 bank conflict) -----
    float* gates = (float*)ring;  // 64x65 f32 overlay on buf0 (free now)
#pragma unroll
    for (int m = 0; m < 2; ++m)
#pragma unroll
      for (int j = 0; j < 4; ++j) {
        int row = wr * 32 + m * 16 + (lane >> 4) * 4 + j;
        int col = wc * 16 + fr;
        gates[row * 65 + col] = acc[m][j];
      }
    __syncthreads();

    float hv[2];
#pragma unroll
    for (int j = 0; j < 2; ++j) {
      int hc = hb2 + j;
      float pi = gates[erow * 65 + hc] + bI[j];
      float pf = gates[erow * 65 + 16 + hc] + bF[j];
      float po = gates[erow * 65 + 32 + hc] + bO[j];
      float pg = gates[erow * 65 + 48 + hc] + bG[j];
      float ig = 1.f / (1.f + __expf(-pi));
      float fg = 1.f / (1.f + __expf(-pf));
      float og = 1.f / (1.f + __expf(-po));
      float gg = 1.f - 2.f / (1.f + __expf(2.f * pg));  // tanh
      float cn = fg * cr[j] + ig * gg;
      cr[j] = cn;
      hv[j] = og * (1.f - 2.f / (1.f + __expf(2.f * cn)));
    }

    // backpressure: slot t%3 previously held h_{t-3}, consumed at step t-2
    if (t >= 3) {
      if (tid == 0) spin_ge(&consCnt[(t - 2) * 4 + mb], 64u);
      __syncthreads();
    }
    if (t < T_DIM - 1) {  // store h_t (bf16 pair) into slot t%3, swizzled
      int hcg = cb * 16 + hb2;
      int kc2 = hcg >> 7, kp = hcg & 127;
      unsigned byte = ((unsigned)(erow * 256 + kp * 2)) ^ ((unsigned)((erow & 7) << 4));
      unsigned pk = (unsigned)f2bf(hv[0]) | ((unsigned)f2bf(hv[1]) << 16);
      unsigned int* hd = (unsigned int*)(hring + (size_t)(t % 3) * 524288 +
                                         (size_t)(mb * 8 + kc2) * BLK + byte);
      __hip_atomic_store(hd, pk, __ATOMIC_RELAXED, __HIP_MEMORY_SCOPE_AGENT);
    }
    asm volatile("s_waitcnt vmcnt(0)" ::: "memory");
    __syncthreads();
    if (tid == 0) {
      if (t < T_DIM - 1)
        __hip_atomic_fetch_add(&prodCnt[t * 4 + mb], 1u, __ATOMIC_RELEASE,
                               __HIP_MEMORY_SCOPE_AGENT);
      if (t >= 1)
        __hip_atomic_fetch_add(&consCnt[t * 4 + mb], 1u, __ATOMIC_RELAXED,
                               __HIP_MEMORY_SCOPE_AGENT);
    }
    if (t == T_DIM - 1) {
      size_t gidx = (size_t)(mb * 64 + erow) * HID_DIM + cb * 16 + hb2;
      *(float2*)(out + gidx) = make_float2(hv[0], hv[1]);
      *(float2*)(out + (size_t)B_DIM * HID_DIM + gidx) = make_float2(cr[0], cr[1]);
    }
  }
}

extern "C" void kernel_launch(void* const* d_in, const int* in_sizes, int n_in,
                              void* d_out, int out_size, void* d_ws, size_t ws_size,
                              hipStream_t stream) {
  (void)in_sizes; (void)n_in; (void)out_size;
  const float* x   = (const float*)d_in[0];
  const float* Wf_ = (const float*)d_in[1];
  const float* bf_ = (const float*)d_in[2];
  const float* Wi_ = (const float*)d_in[3];
  const float* bi_ = (const float*)d_in[4];
  const float* Wo_ = (const float*)d_in[5];
  const float* bo_ = (const float*)d_in[6];
  const float* Wc_ = (const float*)d_in[7];
  const float* bc_ = (const float*)d_in[8];

  unsigned char* ws = (unsigned char*)d_ws;
  unsigned char* Wp = ws;                               // 16 MB packed bf16 W
  size_t off = 16777216;
  float* bp = (float*)(ws + off);          off += 16384;   // packed bias
  unsigned int* prodCnt = (unsigned int*)(ws + off); off += 8192;
  unsigned int* consCnt = (unsigned int*)(ws + off); off += 8192;
  unsigned char* hring = ws + off;         off += 3 * 524288;  // ring-3 h
  unsigned char* xpp = ws + off;           off += 268435456;   // packed x
  if (ws_size < off) return;  // (proven available: round-2 path ran)
  float* out = (float*)d_out;

  prep_pack_w<<<1024, 256, 0, stream>>>(Wi_, Wf_, Wo_, Wc_, Wp);
  prep_bias<<<16, 256, 0, stream>>>(bi_, bf_, bo_, bc_, bp);
  prep_pack_x<<<16384, 256, 0, stream>>>(x, xpp);
  hipMemsetAsync(prodCnt, 0, 16384, stream);  // prod+cons (adjacent)

  hipFuncSetAttribute((const void*)lstm_persist,
                      hipFuncAttributeMaxDynamicSharedMemorySize, 131072);
  const unsigned char* a_xp = xpp;
  const unsigned char* a_wp = Wp;
  const float* a_bp = bp;
  unsigned char* a_hr = hring;
  unsigned int* a_pc = prodCnt;
  unsigned int* a_cc = consCnt;
  float* a_out = out;
  void* args[] = {&a_xp, &a_wp, &a_bp, &a_hr, &a_pc, &a_cc, &a_out};
  hipLaunchCooperativeKernel((const void*)lstm_persist, dim3(256), dim3(512),
                             args, 131072u, stream);
}